// Round 7
// baseline (266.214 us; speedup 1.0000x reference)
//
#include <hip/hip_runtime.h>

#define BATCH 256
#define QN 64
#define HN 2048
#define H2 (HN / 2)            // 1024
#define NROWS (BATCH * QN)     // 16384

typedef float v4f __attribute__((ext_vector_type(4)));
typedef float v2f __attribute__((ext_vector_type(2)));

// Kernel A: factor[k][h] = prod_{j>k} W[k][j][h] * prod_{i<k} W[i][k][h]
__global__ __launch_bounds__(256) void factor_kernel(const float* __restrict__ W,
                                                     float* __restrict__ factor) {
    int idx = blockIdx.x * blockDim.x + threadIdx.x;
    int h2 = idx & (H2 - 1);
    int k  = idx >> 10;
    const v2f* W2 = (const v2f*)W;
    v2f p = {1.f, 1.f};
    #pragma unroll 8
    for (int j = k + 1; j < QN; ++j)
        p *= __builtin_nontemporal_load(&W2[(size_t)(k * QN + j) * H2 + h2]);
    #pragma unroll 8
    for (int i = 0; i < k; ++i)
        p *= __builtin_nontemporal_load(&W2[(size_t)(i * QN + k) * H2 + h2]);
    ((v2f*)factor)[(size_t)k * H2 + h2] = p;   // normal store -> L2/L3 resident
}

// Pass 1: wave per row, pure read stream. inv[row] = 1/max(||x*f||, eps).
// Regular (cached) x loads so x lands in L3 for pass 2.
__global__ __launch_bounds__(256) void sumsq_kernel(const float* __restrict__ x,
                                                    const float* __restrict__ factor,
                                                    float* __restrict__ inv) {
    const int row  = blockIdx.x * 4 + (threadIdx.x >> 6);
    const int lane = threadIdx.x & 63;
    const int q    = row & (QN - 1);

    const v4f* x4 = (const v4f*)(x + (size_t)row * HN);
    const v4f* f4 = (const v4f*)(factor + (size_t)q * HN);

    float ss = 0.f;
    #pragma unroll
    for (int i = 0; i < 8; ++i) {
        v4f a = x4[lane + 64 * i];
        v4f b = f4[lane + 64 * i];
        a *= b;
        ss += a.x * a.x + a.y * a.y + a.z * a.z + a.w * a.w;
    }
    #pragma unroll
    for (int off = 32; off >= 1; off >>= 1)
        ss += __shfl_xor(ss, off, 64);

    if (lane == 0)
        inv[row] = 1.0f / fmaxf(sqrtf(ss), 1e-12f);
}

// Pass 2: pure elementwise stream: out = x * factor[q] * inv[row].
// One block per row; x reads are L3-warm from pass 1; NT stores keep x
// from being evicted by the outgoing write stream.
__global__ __launch_bounds__(256) void scale_kernel(const float* __restrict__ x,
                                                    const float* __restrict__ factor,
                                                    const float* __restrict__ inv,
                                                    float* __restrict__ out) {
    const int row = blockIdx.x;
    const int q   = row & (QN - 1);
    const int t   = threadIdx.x;

    const v4f* x4 = (const v4f*)(x + (size_t)row * HN);
    const v4f* f4 = (const v4f*)(factor + (size_t)q * HN);
    v4f*       o4 = (v4f*)(out + (size_t)row * HN);

    const float iv = inv[row];

    v4f y0 = x4[t]       * f4[t]       * iv;
    v4f y1 = x4[t + 256] * f4[t + 256] * iv;
    __builtin_nontemporal_store(y0, &o4[t]);
    __builtin_nontemporal_store(y1, &o4[t + 256]);
}

extern "C" void kernel_launch(void* const* d_in, const int* in_sizes, int n_in,
                              void* d_out, int out_size, void* d_ws, size_t ws_size,
                              hipStream_t stream) {
    const float* x = (const float*)d_in[0];
    const float* W = (const float*)d_in[1];
    float* out     = (float*)d_out;
    float* factor  = (float*)d_ws;                  // 512 KB
    float* inv     = (float*)d_ws + (size_t)QN * HN; // 64 KB

    factor_kernel<<<(QN * H2) / 256, 256, 0, stream>>>(W, factor);
    sumsq_kernel<<<NROWS / 4, 256, 0, stream>>>(x, factor, inv);
    scale_kernel<<<NROWS, 256, 0, stream>>>(x, factor, inv, out);
}

// Round 8
// 259.320 us; speedup vs baseline: 1.0266x; 1.0266x over previous
//
#include <hip/hip_runtime.h>
#include <stdint.h>

#define BATCH 256
#define QN 64
#define HN 2048
#define H2 (HN / 2)   // 1024
#define WPB 4         // waves per block
#define ROWS 8        // rows per wave -> 512 blocks = 2/CU (64 KB LDS each)

typedef float v4f __attribute__((ext_vector_type(4)));
typedef float v2f __attribute__((ext_vector_type(2)));

typedef __attribute__((address_space(3))) uint32_t lds_u32;
typedef __attribute__((address_space(1))) const uint32_t glb_u32;

// Kernel A: factor[k][h] = prod_{j>k} W[k][j][h] * prod_{i<k} W[i][k][h]
__global__ __launch_bounds__(256) void factor_kernel(const float* __restrict__ W,
                                                     float* __restrict__ factor) {
    int idx = blockIdx.x * blockDim.x + threadIdx.x;
    int h2 = idx & (H2 - 1);
    int k  = idx >> 10;
    const v2f* W2 = (const v2f*)W;
    v2f p = {1.f, 1.f};
    #pragma unroll 8
    for (int j = k + 1; j < QN; ++j)
        p *= __builtin_nontemporal_load(&W2[(size_t)(k * QN + j) * H2 + h2]);
    #pragma unroll 8
    for (int i = 0; i < k; ++i)
        p *= __builtin_nontemporal_load(&W2[(size_t)(i * QN + k) * H2 + h2]);
    ((v2f*)factor)[(size_t)k * H2 + h2] = p;   // normal store -> L2/L3 resident
}

// Kernel B: per-wave barrier-free async pipeline (R6 fixed).
// Each wave: private 2x8KB LDS dbuf, 8 rows, same q (factor in 8 VGPR-quads).
// Steady-state vmcnt queue at loop top: [fill_r(8), stores_{r-1}(8),
// fill_{r+1}(8)] = 24 -> vmcnt(16) waits ONLY fill_r (stores stay in
// flight -- R6's vmcnt(8) wrongly drained them). First/last iter: vmcnt(8).
// 2 blocks/CU x 4 waves x 8KB fill in flight = 64 KB/CU outstanding reads.
__global__ __launch_bounds__(256, 2) void normalize_kernel(const float* __restrict__ x,
                                                           const float* __restrict__ factor,
                                                           float* __restrict__ out) {
    __shared__ float xs[2][WPB][HN];    // 64 KB
    const int t    = threadIdx.x;
    const int wave = t >> 6;
    const int lane = t & 63;
    const int gw   = blockIdx.x * WPB + wave;   // 0..2047
    const int q     = gw & (QN - 1);
    const int bbase = (gw >> 6) * ROWS;         // 32 batch-chunks of 8

    // factor[q] once into registers (compiler inserts its own waits)
    const v4f* f4 = (const v4f*)(factor + (size_t)q * HN);
    v4f b[8];
    #pragma unroll
    for (int i = 0; i < 8; ++i) b[i] = f4[lane + 64 * i];

    // one row fill: 8 x global_load_lds(16B/lane) into this wave's buffer
    auto issue = [&](int r, int buf) {
        const float* src = x + ((size_t)(bbase + r) * QN + q) * HN + lane * 4;
        float* dst = (float*)&xs[buf][wave][0];
        #pragma unroll
        for (int i = 0; i < 8; ++i)
            __builtin_amdgcn_global_load_lds((glb_u32*)(src + i * 256),
                                             (lds_u32*)(dst + i * 256), 16, 0, 0);
    };

    issue(0, 0);
    issue(1, 1);

    #pragma unroll
    for (int r = 0; r < ROWS; ++r) {
        const int buf = r & 1;
        if (r == 0 || r == ROWS - 1)
            asm volatile("s_waitcnt vmcnt(8)" ::: "memory");
        else
            asm volatile("s_waitcnt vmcnt(16)" ::: "memory");

        const v4f* s4 = (const v4f*)&xs[buf][wave][0];
        v4f a[8];
        float ss = 0.f;
        #pragma unroll
        for (int i = 0; i < 8; ++i) {
            a[i] = s4[lane + 64 * i] * b[i];
            ss += a[i].x * a[i].x + a[i].y * a[i].y + a[i].z * a[i].z + a[i].w * a[i].w;
        }
        #pragma unroll
        for (int off = 32; off >= 1; off >>= 1)
            ss += __shfl_xor(ss, off, 64);
        float inv = 1.0f / fmaxf(sqrtf(ss), 1e-12f);

        v4f* o4 = (v4f*)(out + ((size_t)(bbase + r) * QN + q) * HN);
        #pragma unroll
        for (int i = 0; i < 8; ++i) {
            v4f yi = a[i] * inv;
            __builtin_nontemporal_store(yi, &o4[lane + 64 * i]);
        }
        if (r + 2 < ROWS) issue(r + 2, buf);   // refill consumed buffer
    }
}

extern "C" void kernel_launch(void* const* d_in, const int* in_sizes, int n_in,
                              void* d_out, int out_size, void* d_ws, size_t ws_size,
                              hipStream_t stream) {
    const float* x = (const float*)d_in[0];
    const float* W = (const float*)d_in[1];
    float* out     = (float*)d_out;
    float* factor  = (float*)d_ws;   // QN*HN floats = 512 KB

    factor_kernel<<<(QN * H2) / 256, 256, 0, stream>>>(W, factor);
    normalize_kernel<<<(BATCH * QN) / (WPB * ROWS), 256, 0, stream>>>(x, factor, out);
}